// Round 7
// baseline (189.967 us; speedup 1.0000x reference)
//
#include <hip/hip_runtime.h>

typedef unsigned short u16;
typedef __bf16 bf16x8 __attribute__((ext_vector_type(8)));
typedef __bf16 bf16x4 __attribute__((ext_vector_type(4)));
typedef __bf16 bf16x2 __attribute__((ext_vector_type(2)));
typedef short s16x4 __attribute__((ext_vector_type(4)));
typedef float f32x4 __attribute__((ext_vector_type(4)));

#define Mdim 4096
#define Ndim 1024
#define Kdim 1024

__device__ __forceinline__ u16 f2bf(float f) {
    unsigned u = __float_as_uint(f);
    u += 0x7FFF + ((u >> 16) & 1);   // RNE
    return (u16)(u >> 16);
}

// async global->LDS, 16B/lane (used by out_gemm only)
__device__ __forceinline__ void gl_lds16(const u16* g, u16* l) {
    __builtin_amdgcn_global_load_lds(
        (const __attribute__((address_space(1))) unsigned int*)g,
        (__attribute__((address_space(3))) unsigned int*)l, 16, 0, 0);
}

__device__ __forceinline__ f32x4 mfma16(s16x4 a, s16x4 b, f32x4 c) {
#if __has_builtin(__builtin_amdgcn_mfma_f32_16x16x16_bf16)
    return __builtin_amdgcn_mfma_f32_16x16x16_bf16(
        __builtin_bit_cast(bf16x4, a), __builtin_bit_cast(bf16x4, b), c, 0, 0, 0);
#else
    return __builtin_amdgcn_mfma_f32_16x16x16bf16_1k(a, b, c, 0, 0, 0);
#endif
}

#if __has_builtin(__builtin_amdgcn_exp2f)
#define EXP2(x) __builtin_amdgcn_exp2f(x)
#else
#define EXP2(x) exp2f(x)
#endif

__device__ __forceinline__ s16x4 pack4bf(float a, float b, float c, float d) {
#if __has_builtin(__builtin_amdgcn_cvt_pk_bf16_f32)
    union { struct { bf16x2 lo, hi; } v; s16x4 s; } u;
    u.v.lo = __builtin_amdgcn_cvt_pk_bf16_f32(a, b);
    u.v.hi = __builtin_amdgcn_cvt_pk_bf16_f32(c, d);
    return u.s;
#else
    s16x4 r;
    r.x = (short)f2bf(a); r.y = (short)f2bf(b);
    r.z = (short)f2bf(c); r.w = (short)f2bf(d);
    return r;
#endif
}

// ---------------------------------------------------------------------------
// Kernel 1: cast fp32 -> bf16 AND swizzle X, Wq, Wk, Wv into MFMA-fragment
// order: elem (row,col) -> [(row>>4)][(col>>5)][(col>>3)&3][row&15][col&7]
// (one 16x32 fragment tile = 512 contiguous elems; a wave's dwordx4 load of
// a fragment is one dense 1KB block).  Wo stays row-major (out_gemm is LDS-
// staged).  Each thread: 8 consecutive col elems -> one 16B store.
// ---------------------------------------------------------------------------
__global__ __launch_bounds__(256) void cast_swz(
    const float* __restrict__ X,
    const float* __restrict__ Wq, const float* __restrict__ Wk,
    const float* __restrict__ Wv, const float* __restrict__ Wo,
    u16* __restrict__ Xf,
    u16* __restrict__ Wqf, u16* __restrict__ Wkf,
    u16* __restrict__ Wvf, u16* __restrict__ Wob) {
    size_t flat = ((size_t)blockIdx.x * 256 + threadIdx.x) * 8;
    const float* src;
    u16* dst;
    size_t soff;
    int row = 0, col = 0;
    bool frag;
    if (flat < 4194304) {            // X: 4M elems
        src = X; dst = Xf; soff = flat;
        row = (int)(flat >> 10); col = (int)(flat & 1023); frag = true;
    } else {
        size_t r = flat - 4194304;
        if (r < 3145728) {           // Wq/Wk/Wv: 1M each
            int wsel = (int)(r >> 20);
            soff = r & 1048575;
            src = (wsel == 0) ? Wq : (wsel == 1) ? Wk : Wv;
            dst = (wsel == 0) ? Wqf : (wsel == 1) ? Wkf : Wvf;
            row = (int)(soff >> 10); col = (int)(soff & 1023); frag = true;
        } else {                     // Wo plain
            soff = r - 3145728;
            src = Wo; dst = Wob; frag = false;
        }
    }
    float4 v0 = *(const float4*)(src + soff);
    float4 v1 = *(const float4*)(src + soff + 4);
    u16 t[8];
    t[0] = f2bf(v0.x); t[1] = f2bf(v0.y); t[2] = f2bf(v0.z); t[3] = f2bf(v0.w);
    t[4] = f2bf(v1.x); t[5] = f2bf(v1.y); t[6] = f2bf(v1.z); t[7] = f2bf(v1.w);
    size_t doff = frag
        ? ((((size_t)(row >> 4) * 32 + (col >> 5)) * 4 + ((col >> 3) & 3)) * 128
           + (size_t)(row & 15) * 8)
        : soff;
    *(uint4*)(dst + doff) = *(uint4*)t;
}

// ---------------------------------------------------------------------------
// Fused QKV GEMM v3: fully register-direct (zero LDS, zero barriers).
// A = Xf (A-op frag order), B = Wf (B-op frag order); per k-iter: 8 dense
// dwordx4 loads + 16 MFMA; register ping-pong with s_waitcnt vmcnt(8).
// Grid (32, 24): y<8 -> Q, y<16 -> K, else -> V; 2x2 wave grid per block.
// Epilogues write Q/K/V in flash-fragment order (same as R6, verified).
// ---------------------------------------------------------------------------
__global__ __launch_bounds__(256, 3) void qkv_gemm(
    const u16* __restrict__ Xf,
    const u16* __restrict__ Wqf, const u16* __restrict__ Wkf, const u16* __restrict__ Wvf,
    const float* __restrict__ bq, const float* __restrict__ bk, const float* __restrict__ bv,
    u16* __restrict__ Qw, u16* __restrict__ Kw, u16* __restrict__ Vw) {
    const int y = blockIdx.y;
    const int z = y >> 3;
    const int n0 = (y & 7) * 128;
    const u16* Wf = (z == 0) ? Wqf : (z == 1) ? Wkf : Wvf;
    const float* bias = (z == 0) ? bq : (z == 1) ? bk : bv;

    const int tid = threadIdx.x, w = tid >> 6, lane = tid & 63;
    const int quad = lane >> 4, l16 = lane & 15;
    const int wm = w & 1, wn = w >> 1;
    const int m0 = blockIdx.x * 128;

    const u16* Af = Xf + ((size_t)(m0 >> 4) + wm * 4) * 16384;  // frag tile row = 32*512
    const u16* Bf = Wf + ((size_t)(n0 >> 4) + wn * 4) * 16384;

    f32x4 acc[4][4] = {};
    bf16x8 aA[4], bA[4], aB[4], bB[4];

#define QLOAD(kt_, a_, b_)                                                     \
    {                                                                          \
        _Pragma("unroll")                                                      \
        for (int i_ = 0; i_ < 4; ++i_) {                                       \
            a_[i_] = *(const bf16x8*)(Af + ((size_t)i_ * 32 + (kt_)) * 512 + lane * 8); \
            b_[i_] = *(const bf16x8*)(Bf + ((size_t)i_ * 32 + (kt_)) * 512 + lane * 8); \
        }                                                                      \
    }
#define QCOMP(a_, b_)                                                          \
    {                                                                          \
        _Pragma("unroll")                                                      \
        for (int mt_ = 0; mt_ < 4; ++mt_)                                      \
            _Pragma("unroll")                                                  \
            for (int nt_ = 0; nt_ < 4; ++nt_)                                  \
                acc[mt_][nt_] = __builtin_amdgcn_mfma_f32_16x16x32_bf16(       \
                    a_[mt_], b_[nt_], acc[mt_][nt_], 0, 0, 0);                 \
    }

    QLOAD(0, aA, bA);
#pragma unroll 1
    for (int kt = 0; kt < 32; kt += 2) {
        QLOAD(kt + 1, aB, bB);                       // kt+1 <= 31 always
        asm volatile("s_waitcnt vmcnt(8)" ::: "memory");
        QCOMP(aA, bA);
        if (kt + 2 < 32) {
            QLOAD(kt + 2, aA, bA);
            asm volatile("s_waitcnt vmcnt(8)" ::: "memory");
        } else {
            asm volatile("s_waitcnt vmcnt(0)" ::: "memory");
        }
        QCOMP(aB, bB);
    }

    // epilogue: write flash-fragment order (identical to R6 modes 2/3/4)
#pragma unroll
    for (int nt = 0; nt < 4; ++nt) {
        int n = n0 + wn * 64 + nt * 16 + l16;
        float bb = bias[n];
        const int h = n >> 6, d = n & 63;
        const int ksf = (d >> 5) & 1, quadf8 = (d >> 3) & 3, jj = d & 7;
        const int dtf = d >> 4, l16f = d & 15;
#pragma unroll
        for (int mt = 0; mt < 4; ++mt) {
            int mbase = m0 + wm * 64 + mt * 16 + quad * 4;
            if (z == 2) {
                int b = mbase >> 11, t = mbase & 2047;
                int kt = t >> 5, kl = t & 31;
                int c = kl >> 4, quadf = (kl >> 2) & 3;
                ushort4 pk;
                pk.x = f2bf(acc[mt][nt][0] + bb);
                pk.y = f2bf(acc[mt][nt][1] + bb);
                pk.z = f2bf(acc[mt][nt][2] + bb);
                pk.w = f2bf(acc[mt][nt][3] + bb);
                *(ushort4*)&Vw[(size_t)(b * 16 + h) * 131072 + kt * 2048 +
                               (c * 4 + dtf) * 256 + (quadf * 16 + l16f) * 4] = pk;
            } else {
                u16* out = (z == 0) ? Qw : Kw;
#pragma unroll
                for (int r = 0; r < 4; ++r) {
                    int m = mbase + r;
                    int b = m >> 11, t = m & 2047;
                    int blk = t >> 5, tl = t & 31;
                    int cq = tl >> 4, l16q = tl & 15;
                    out[(size_t)(b * 16 + h) * 131072 + blk * 2048 +
                        (cq * 2 + ksf) * 512 + (quadf8 * 16 + l16q) * 8 + jj] =
                        f2bf(acc[mt][nt][r] + bb);
                }
            }
        }
    }
}

// ---------------------------------------------------------------------------
// out_gemm: unchanged m97-style LDS-staged GEMM (mode 1), BN=64.
// ---------------------------------------------------------------------------
__global__ __launch_bounds__(256, 2) void out_gemm(
    const u16* __restrict__ A, const u16* __restrict__ Bw,
    const float* __restrict__ bias, float* __restrict__ out) {
    constexpr int BN = 64;
    __shared__ __align__(16) u16 At[128 * 64];
    __shared__ __align__(16) u16 Bt[BN * 64];
    const int tid = threadIdx.x, w = tid >> 6, lane = tid & 63;
    const int quad = lane >> 4, l16 = lane & 15;
    const int wm = w & 1, wn = w >> 1;
    const int m0 = blockIdx.x * 128, n0 = blockIdx.y * BN;
    constexpr int NTN = BN / 32;
    f32x4 acc[4][NTN] = {};
    const int r8 = lane >> 3, c8 = lane & 7;

    for (int k0 = 0; k0 < Kdim; k0 += 64) {
        __syncthreads();
#pragma unroll
        for (int i = 0; i < 4; ++i) {
            int row = w * 32 + i * 8 + r8;
            int j = c8 ^ (row & 7);
            gl_lds16(A + (size_t)(m0 + row) * Kdim + k0 + j * 8,
                     &At[(w * 32 + i * 8) * 64]);
        }
#pragma unroll
        for (int i = 0; i < BN / 32; ++i) {
            int row = w * (BN / 4) + i * 8 + r8;
            int j = c8 ^ (row & 7);
            gl_lds16(Bw + (size_t)(n0 + row) * Kdim + k0 + j * 8,
                     &Bt[(w * (BN / 4) + i * 8) * 64]);
        }
        __syncthreads();
#pragma unroll
        for (int ks = 0; ks < 2; ++ks) {
            bf16x8 af[4], bf[NTN];
#pragma unroll
            for (int mt = 0; mt < 4; ++mt) {
                int r = wm * 64 + mt * 16 + l16;
                af[mt] = *(const bf16x8*)&At[r * 64 + ((ks * 4 + quad) ^ (r & 7)) * 8];
            }
#pragma unroll
            for (int nt = 0; nt < NTN; ++nt) {
                int r = wn * (BN / 2) + nt * 16 + l16;
                bf[nt] = *(const bf16x8*)&Bt[r * 64 + ((ks * 4 + quad) ^ (r & 7)) * 8];
            }
#pragma unroll
            for (int mt = 0; mt < 4; ++mt)
#pragma unroll
                for (int nt = 0; nt < NTN; ++nt)
                    acc[mt][nt] = __builtin_amdgcn_mfma_f32_16x16x32_bf16(
                        af[mt], bf[nt], acc[mt][nt], 0, 0, 0);
        }
    }
#pragma unroll
    for (int nt = 0; nt < NTN; ++nt) {
        int n = n0 + wn * (BN / 2) + nt * 16 + l16;
        float bb = bias[n];
#pragma unroll
        for (int mt = 0; mt < 4; ++mt) {
            int mbase = m0 + wm * 64 + mt * 16 + quad * 4;
#pragma unroll
            for (int r = 0; r < 4; ++r)
                out[(size_t)(mbase + r) * Ndim + n] = acc[mt][nt][r] + bb;
        }
    }
}

// ---------------------------------------------------------------------------
// Flash attention v7: one strip per WAVE, 4 consecutive strips per block.
// The 4 waves march the same kt sequence in lockstep -> L1 dedups K/V loads
// 4x.  Zero LDS, zero barriers, register ping-pong with vmcnt(12).
// Grid 512 = 16 strip-groups x 32 bh, heavy groups first.
// ---------------------------------------------------------------------------
__global__ __launch_bounds__(256, 2) void flash_attn(
    const u16* __restrict__ QF, const u16* __restrict__ KF,
    const u16* __restrict__ VF, u16* __restrict__ Aatt) {
    const int tid = threadIdx.x, w = tid >> 6, lane = tid & 63;
    const int quad = lane >> 4, l16 = lane & 15;
    const int g = blockIdx.x;
    const int bh = g & 31;
    const int sg = g >> 5;                    // 0 = heaviest group
    const int strip = (15 - sg) * 4 + w;      // this wave's strip (0..63)
    const int qbase = strip * 32;
    const int ntw = strip + 1;

    const u16* QFh = QF + (size_t)bh * 131072;
    const u16* KFh = KF + (size_t)bh * 131072;
    const u16* VFh = VF + (size_t)bh * 131072;
    const int b = bh >> 4, h = bh & 15;
    const float c1 = 0.18033688011112042f;    // log2(e)/8

    bf16x8 qf[2][2];
#pragma unroll
    for (int qt = 0; qt < 2; ++qt)
#pragma unroll
        for (int ks = 0; ks < 2; ++ks)
            qf[qt][ks] = *(const bf16x8*)(QFh + (size_t)strip * 2048 +
                                          (qt * 2 + ks) * 512 + lane * 8);

    f32x4 o[2][4] = {};
    float lsum[2] = {0.f, 0.f};

#define LOADT(kt_, ka_, vf_)                                                   \
    {                                                                          \
        const u16* kp_ = KFh + (size_t)(kt_) * 2048;                           \
        const u16* vp_ = VFh + (size_t)(kt_) * 2048;                           \
        _Pragma("unroll")                                                      \
        for (int c_ = 0; c_ < 2; ++c_) {                                       \
            _Pragma("unroll")                                                  \
            for (int ks_ = 0; ks_ < 2; ++ks_)                                  \
                ka_[c_][ks_] = *(const bf16x8*)(kp_ + (c_ * 2 + ks_) * 512     \
                                                + lane * 8);                   \
            _Pragma("unroll")                                                  \
            for (int dt_ = 0; dt_ < 4; ++dt_)                                  \
                vf_[c_][dt_] = *(const s16x4*)(vp_ + (c_ * 4 + dt_) * 256      \
                                               + lane * 4);                    \
        }                                                                      \
    }

#define COMPUTE(kt_, ka_, vf_)                                                 \
    {                                                                          \
        const bool dm_ = ((kt_) == ntw - 1);                                   \
        _Pragma("unroll")                                                      \
        for (int c_ = 0; c_ < 2; ++c_) {                                       \
            _Pragma("unroll")                                                  \
            for (int qt_ = 0; qt_ < 2; ++qt_) {                                \
                f32x4 z_ = {};                                                 \
                z_ = __builtin_amdgcn_mfma_f32_16x16x32_bf16(                  \
                    ka_[c_][0], qf[qt_][0], z_, 0, 0, 0);                      \
                z_ = __builtin_amdgcn_mfma_f32_16x16x32_bf16(                  \
                    ka_[c_][1], qf[qt_][1], z_, 0, 0, 0);                      \
                float p_[4];                                                   \
                if (dm_) {                                                     \
                    int q_ = qbase + qt_ * 16 + l16;                           \
                    int kkb_ = (kt_) * 32 + c_ * 16 + quad * 4;                \
                    _Pragma("unroll")                                          \
                    for (int r_ = 0; r_ < 4; ++r_)                             \
                        p_[r_] = (kkb_ + r_ > q_) ? 0.f : EXP2(z_[r_] * c1);   \
                } else {                                                       \
                    _Pragma("unroll")                                          \
                    for (int r_ = 0; r_ < 4; ++r_) p_[r_] = EXP2(z_[r_] * c1); \
                }                                                              \
                lsum[qt_] += (p_[0] + p_[1]) + (p_[2] + p_[3]);                \
                s16x4 pa_ = pack4bf(p_[0], p_[1], p_[2], p_[3]);               \
                _Pragma("unroll")                                              \
                for (int dt_ = 0; dt_ < 4; ++dt_)                              \
                    o[qt_][dt_] = mfma16(pa_, vf_[c_][dt_], o[qt_][dt_]);      \
            }                                                                  \
        }                                                                      \
    }

    bf16x8 kaA[2][2], kaB[2][2];
    s16x4 vfA[2][4], vfB[2][4];
    {
        int kt = 0;
        LOADT(0, kaA, vfA);
#pragma unroll 1
        while (true) {
            if (kt + 1 < ntw) {
                LOADT(kt + 1, kaB, vfB);
                asm volatile("s_waitcnt vmcnt(12)" ::: "memory");
            } else {
                asm volatile("s_waitcnt vmcnt(0)" ::: "memory");
            }
            COMPUTE(kt, kaA, vfA);
            ++kt;
            if (kt >= ntw) break;
            if (kt + 1 < ntw) {
                LOADT(kt + 1, kaA, vfA);
                asm volatile("s_waitcnt vmcnt(12)" ::: "memory");
            } else {
                asm volatile("s_waitcnt vmcnt(0)" ::: "memory");
            }
            COMPUTE(kt, kaB, vfB);
            ++kt;
            if (kt >= ntw) break;
        }
    }

    // per-wave epilogue: l across quads via shuffles, direct store
#pragma unroll
    for (int qt = 0; qt < 2; ++qt) {
        float l = lsum[qt];
        l += __shfl_xor(l, 16);
        l += __shfl_xor(l, 32);
        float inv = 1.0f / l;
        float rinv[4];
#pragma unroll
        for (int r = 0; r < 4; ++r)
            rinv[r] = __shfl(inv, (lane & 48) + quad * 4 + r);
#pragma unroll
        for (int dt = 0; dt < 4; ++dt) {
            int e = h * 64 + dt * 16 + l16;
#pragma unroll
            for (int r = 0; r < 4; ++r) {
                int t = qbase + qt * 16 + quad * 4 + r;
                Aatt[((size_t)(b * 2048 + t)) * 1024 + e] = f2bf(o[qt][dt][r] * rinv[r]);
            }
        }
    }
}

// ---------------------------------------------------------------------------
extern "C" void kernel_launch(void* const* d_in, const int* in_sizes, int n_in,
                              void* d_out, int out_size, void* d_ws, size_t ws_size,
                              hipStream_t stream) {
    const float* X  = (const float*)d_in[0];
    const float* Wq = (const float*)d_in[1];
    const float* bq = (const float*)d_in[2];
    const float* Wk = (const float*)d_in[3];
    const float* bk = (const float*)d_in[4];
    const float* Wv = (const float*)d_in[5];
    const float* bv = (const float*)d_in[6];
    const float* Wo = (const float*)d_in[7];
    const float* bo = (const float*)d_in[8];

    char* ws = (char*)d_ws;
    const size_t MB = 1 << 20;
    u16* Xf   = (u16*)(ws);             // X in A-op fragment order
    u16* Wqf  = (u16*)(ws + 8  * MB);   // W in B-op fragment order
    u16* Wkf  = (u16*)(ws + 10 * MB);
    u16* Wvf  = (u16*)(ws + 12 * MB);
    u16* Wob  = (u16*)(ws + 14 * MB);   // Wo row-major bf16
    u16* Qw   = (u16*)(ws + 16 * MB);   // flash B-op order
    u16* Kw   = (u16*)(ws + 24 * MB);   // flash A-op order
    u16* Vw   = (u16*)(ws + 32 * MB);   // flash PV B-op order
    u16* Aatt = (u16*)(ws + 40 * MB);   // [B][T][E] row-major

    cast_swz<<<4096, 256, 0, stream>>>(X, Wq, Wk, Wv, Wo, Xf, Wqf, Wkf, Wvf, Wob);
    qkv_gemm<<<dim3(32, 24), 256, 0, stream>>>(Xf, Wqf, Wkf, Wvf, bq, bk, bv, Qw, Kw, Vw);
    flash_attn<<<dim3(512), 256, 0, stream>>>(Qw, Kw, Vw, Aatt);
    out_gemm<<<dim3(32, 16), 256, 0, stream>>>(Aatt, Wob, bo, (float*)d_out);
}